// Round 12
// baseline (4067.402 us; speedup 1.0000x reference)
//
#include <hip/hip_runtime.h>
#include <float.h>

// CloudNet (PointNet++-ish) pipeline on MI355X — persistent-block producer/
// consumer megakernels. Correctness contract: FPS + radius selection bit-exact
// vs numpy f32 (no FMA contraction -> contract(off) + __f*_rn; argmax/top_k
// ties -> lowest index). MLP math free to use pk-FMA.
//
// R12: mega1 = fps1 + rc1 (84KB pad -> producers own their CU; grid 128 to
// keep most CUs idle -> clock headroom for the serial fps spine).
//      mega2 = fps2 + rc2 (NO pad, 4 blocks/CU -> rc2 latency hiding).
//      fps: float4 s_xyz broadcast fetch, batched coord writeout (1 in-loop
//      global store: the pub astore consumers poll).

typedef float f32x2 __attribute__((ext_vector_type(2)));

__device__ __forceinline__ float d2_rn(float ax, float ay, float az,
                                       float bx, float by, float bz) {
  float dx = __fsub_rn(ax, bx), dy = __fsub_rn(ay, by), dz = __fsub_rn(az, bz);
  return __fadd_rn(__fadd_rn(__fmul_rn(dx, dx), __fmul_rn(dy, dy)), __fmul_rn(dz, dz));
}

template<int CTRL>
__device__ __forceinline__ unsigned long long dppmax(unsigned long long a) {
  const unsigned int lo = (unsigned int)a, hi = (unsigned int)(a >> 32);
  const unsigned int slo =
      (unsigned int)__builtin_amdgcn_update_dpp(0, (int)lo, CTRL, 0xf, 0xf, true);
  const unsigned int shi =
      (unsigned int)__builtin_amdgcn_update_dpp(0, (int)hi, CTRL, 0xf, 0xf, true);
  const unsigned long long s = ((unsigned long long)shi << 32) | slo;
  return s > a ? s : a;
}

__device__ __forceinline__ unsigned int aload(const unsigned int* p) {
  return __hip_atomic_load(p, __ATOMIC_RELAXED, __HIP_MEMORY_SCOPE_AGENT);
}
__device__ __forceinline__ void astore(unsigned int* p, unsigned int v) {
  __hip_atomic_store(p, v, __ATOMIC_RELAXED, __HIP_MEMORY_SCOPE_AGENT);
}

// Barrier that drains only LDS (lgkm) — NOT vmcnt (no store-ack stall).
__device__ __forceinline__ void barrier_lgkm() {
  asm volatile("s_waitcnt lgkmcnt(0)\n\ts_barrier" ::: "memory");
}

// ---------------- FPS core (T=256, pk-f32 distance, DPP ladder) -------------
// Key = (f32_bits(mind)<<32) | (N-1-idx): u64 max == argmax with numpy's
// lowest-index tie-break (d2>=0 -> float bits order-isomorphic; bigger
// N-1-idx wins ties = lower index). Publishes sample idx (idx+1, 0=empty)
// via relaxed device-scope atomic; coords written batched at the end
// (consumers derive coords from the immutable source array via pub).
template<int N, int NS, int T>
__device__ void fps_core(float4* sxyz, int* s_idx,
                         unsigned long long* s_red,
                         float* __restrict__ outp,
                         unsigned int* __restrict__ pub) {
#pragma clang fp contract(off)
  constexpr int P = N / T;
  constexpr int P2 = P / 2;
  constexpr int W = T / 64;
  const int t = threadIdx.x;
  __builtin_amdgcn_s_setprio(2);
  f32x2 px[P2], py[P2], pz[P2], mind[P2];
  unsigned int kc0[P2], kc1[P2];
#pragma unroll
  for (int j = 0; j < P2; ++j) {
    const int i0 = (2*j)*T + t, i1 = i0 + T;
    const float4 c0 = sxyz[i0], c1 = sxyz[i1];
    px[j] = f32x2{c0.x, c1.x};
    py[j] = f32x2{c0.y, c1.y};
    pz[j] = f32x2{c0.z, c1.z};
    mind[j] = f32x2{FLT_MAX, FLT_MAX};    // ref inits to finfo(f32).max
    kc0[j] = (unsigned int)(N - 1 - i0);
    kc1[j] = (unsigned int)(N - 1 - i1);
  }
  float lx = sxyz[0].x, ly = sxyz[0].y, lz = sxyz[0].z;  // start at point 0
  if (t == 0) { s_idx[0] = 0; astore(&pub[0], 1u); }
  for (int it = 1; it < NS; ++it) {
    const f32x2 lx2 = {lx, lx}, ly2 = {ly, ly}, lz2 = {lz, lz};
    float bv0 = -1.0f, bv1 = -1.0f;
    unsigned int bk0 = 0, bk1 = 0;
#pragma unroll
    for (int j = 0; j < P2; ++j) {
      // contract(off): separate pk_mul/pk_add — bit-exact vs numpy ufuncs
      const f32x2 dx = px[j] - lx2;
      const f32x2 dy = py[j] - ly2;
      const f32x2 dz = pz[j] - lz2;
      const f32x2 s = ((dx*dx) + (dy*dy)) + (dz*dz);
      const float m0 = fminf(mind[j].x, s.x);
      const float m1 = fminf(mind[j].y, s.y);
      mind[j] = f32x2{m0, m1};
      const bool g0 = m0 > bv0;   // strict > => lowest j (= lowest idx) wins
      bv0 = g0 ? m0 : bv0; bk0 = g0 ? kc0[j] : bk0;
      const bool g1 = m1 > bv1;
      bv1 = g1 ? m1 : bv1; bk1 = g1 ? kc1[j] : bk1;
    }
    const unsigned long long k0 = ((unsigned long long)__float_as_uint(bv0) << 32) | bk0;
    const unsigned long long k1 = ((unsigned long long)__float_as_uint(bv1) << 32) | bk1;
    unsigned long long key = k0 > k1 ? k0 : k1;   // ties: larger kc = lower idx
    key = dppmax<0x111>(key);  // row_shr:1
    key = dppmax<0x112>(key);  // row_shr:2
    key = dppmax<0x114>(key);  // row_shr:4
    key = dppmax<0x118>(key);  // row_shr:8
    key = dppmax<0x142>(key);  // row_bcast:15
    key = dppmax<0x143>(key);  // row_bcast:31  -> lane 63 holds wave max
    const int par = it & 1;
    if ((t & 63) == 63) s_red[par*W + (t >> 6)] = key;
    barrier_lgkm();
    unsigned long long best = s_red[par*W];
#pragma unroll
    for (int w = 1; w < W; ++w) {
      const unsigned long long o = s_red[par*W + w];
      best = o > best ? o : best;
    }
    const int idx = (N - 1) - (int)(unsigned int)(best & 0xFFFFFFFFull);
    // publish early: next-iter VALU covers store latency (no vm drain at barrier)
    if (t == 0) { astore(&pub[it], (unsigned int)(idx + 1)); s_idx[it] = idx; }
    const float4 c = sxyz[idx];           // single b128 broadcast
    lx = c.x; ly = c.y; lz = c.z;
  }
  __builtin_amdgcn_s_setprio(0);
  __syncthreads();
  for (int s = t; s < NS; s += T) {       // batched coord writeout
    const float4 c = sxyz[s_idx[s]];
    outp[(size_t)s*3 + 0] = c.x; outp[(size_t)s*3 + 1] = c.y; outp[(size_t)s*3 + 2] = c.z;
  }
}

// ----------------------------- LDS layouts ----------------------------------
struct FpsSm1 { float4 xyz[4096]; int idx[2048]; unsigned long long red[8]; };
struct FpsSm2 { float4 xyz[2048]; int idx[512];  unsigned long long red[8]; };
struct SmRC1 {
  union { struct { float d2[1024]; int id[1024]; } rad; float x[64 * 64]; } u;
  float rel[64 * 4];
  float out[128];
  int nid[64];
  int qidx;
  int cnt;
};
struct SmRC2 {
  union { struct { float d2[1024]; int id[1024]; } rad; float x[64 * 128]; } u;
  float rel[64 * 4];
  float out[256];
  int nid[64];
  int qidx;
  int cnt;
};
// mega1 padded: 1 block/CU so fps1 producers own their CU.
union Mega1Sm { FpsSm1 f; SmRC1 r; char pad[84 * 1024]; };
// mega2 NOT padded: ~35KB -> 4 blocks/CU (rc2 needs co-residency to hide
// weight-load latency; R11 proved 1 block/CU costs 3-5x on conv2).
union Mega2Sm { FpsSm2 f; SmRC2 r; };

// ------------- rc1 item: radius(r=0.1 over points) + conv1 (256 thr) --------
__device__ void rc1_item(int b, int m,
                         const float* __restrict__ points,
                         const unsigned int* __restrict__ sidx1, float r2,
                         const float* __restrict__ w1, const float* __restrict__ b1,
                         const float* __restrict__ w2, const float* __restrict__ b2,
                         const float* __restrict__ w3, const float* __restrict__ b3,
                         float* __restrict__ x1, SmRC1& R) {
  const int t = threadIdx.x;
  const int q = b*2048 + m;
  if (t == 0) {
    unsigned int v;
    while ((v = aload(&sidx1[q])) == 0u) __builtin_amdgcn_s_sleep(16);
    R.qidx = (int)v - 1;
    R.cnt = 0;
  }
  __syncthreads();
  const float* pb = points + (size_t)b * 4096 * 3;
  const int qi = R.qidx;
  const float qx = pb[qi*3], qy = pb[qi*3+1], qz = pb[qi*3+2];
  for (int i = t; i < 4096; i += 256) {
    const float d2 = d2_rn(qx, qy, qz, pb[i*3], pb[i*3+1], pb[i*3+2]);
    if (d2 <= r2) {
      const int p = atomicAdd(&R.cnt, 1);
      if (p < 1024) { R.u.rad.d2[p] = d2; R.u.rad.id[p] = i; }
    }
  }
  __syncthreads();
  const int cntc = min(R.cnt, 1024);
  const int cnt = min(cntc, 64);
  float* outp = x1 + (size_t)q * 128;
  if (cnt == 0) { if (t < 128) outp[t] = 0.f; return; }
  if (cntc <= 64) {
    if (t < cntc) R.nid[t] = R.u.rad.id[t];     // set equality suffices (max-agg)
  } else {
    // top_k(-d2): smallest d2, ties -> lower index. (d2,idx) lex rank < 64.
    for (int c = t; c < cntc; c += 256) {
      const float dc = R.u.rad.d2[c]; const int ic = R.u.rad.id[c];
      int rank = 0;
      for (int jj = 0; jj < cntc; ++jj)
        rank += (R.u.rad.d2[jj] < dc) || (R.u.rad.d2[jj] == dc && R.u.rad.id[jj] < ic);
      if (rank < 64) R.nid[rank] = ic;
    }
  }
  __syncthreads();
  if (t < 64) {
    const int n = (t < cnt) ? R.nid[t] : 0;     // finite filler row
    const float* p = points + ((size_t)(b << 12) + n) * 3;
    R.rel[t*4+0] = p[0] - qx; R.rel[t*4+1] = p[1] - qy; R.rel[t*4+2] = p[2] - qz;
  }
  __syncthreads();
  // conv1: rel(3)->64->64->128, 4 waves x 16-ch slices, h in LDS (5-bit XOR)
  const int j = t & 63;
  const int g = __builtin_amdgcn_readfirstlane(t >> 6);
  float* s_x = R.u.x;    // overlays rad (done)
  const int sw  = j & 31;
  const int row = j * 64;
  const float rx = R.rel[j*4+0], ry = R.rel[j*4+1], rz = R.rel[j*4+2];
  f32x2 acc[8];
  { const f32x2* bv = (const f32x2*)(b1 + g*16);
#pragma unroll
    for (int c = 0; c < 8; ++c) acc[c] = bv[c]; }
#pragma unroll
  for (int kk = 0; kk < 3; ++kk) {
    const float xk = (kk == 0) ? rx : ((kk == 1) ? ry : rz);
    const f32x2 xv = {xk, xk};
    const float4* wr = (const float4*)(w1 + kk*64 + g*16);
#pragma unroll
    for (int c4 = 0; c4 < 4; ++c4) {
      const float4 w = wr[c4];
      acc[c4*2+0] += xv * f32x2{w.x, w.y};
      acc[c4*2+1] += xv * f32x2{w.z, w.w};
    }
  }
#pragma unroll
  for (int c = 0; c < 8; ++c) {
    const f32x2 v = acc[c];
    s_x[row + ((g*16 + 2*c + 0) ^ sw)] = fmaxf(v.x, 0.f);
    s_x[row + ((g*16 + 2*c + 1) ^ sw)] = fmaxf(v.y, 0.f);
  }
  __syncthreads();
  { const f32x2* bv = (const f32x2*)(b2 + g*16);
#pragma unroll
    for (int c = 0; c < 8; ++c) acc[c] = bv[c]; }
#pragma unroll 2
  for (int k = 0; k < 64; ++k) {
    const float hk = s_x[row + (k ^ sw)];
    const f32x2 hv = {hk, hk};
    const float4* wr = (const float4*)(w2 + k*64 + g*16);
#pragma unroll
    for (int c4 = 0; c4 < 4; ++c4) {
      const float4 w = wr[c4];
      acc[c4*2+0] += hv * f32x2{w.x, w.y};
      acc[c4*2+1] += hv * f32x2{w.z, w.w};
    }
  }
  __syncthreads();   // all L2 reads of h1 done
#pragma unroll
  for (int c = 0; c < 8; ++c) {
    const f32x2 v = acc[c];
    s_x[row + ((g*16 + 2*c + 0) ^ sw)] = fmaxf(v.x, 0.f);
    s_x[row + ((g*16 + 2*c + 1) ^ sw)] = fmaxf(v.y, 0.f);
  }
  __syncthreads();
#pragma unroll 1
  for (int p = 0; p < 2; ++p) {
    f32x2 a[8];
    { const f32x2* bv = (const f32x2*)(b3 + g*32 + p*16);
#pragma unroll
      for (int c = 0; c < 8; ++c) a[c] = bv[c]; }
#pragma unroll 2
    for (int k = 0; k < 64; ++k) {
      const float hk = s_x[row + (k ^ sw)];
      const f32x2 hv = {hk, hk};
      const float4* wr = (const float4*)(w3 + k*128 + g*32 + p*16);
#pragma unroll
      for (int c4 = 0; c4 < 4; ++c4) {
        const float4 w = wr[c4];
        a[c4*2+0] += hv * f32x2{w.x, w.y};
        a[c4*2+1] += hv * f32x2{w.z, w.w};
      }
    }
    if (j >= cnt) {
#pragma unroll
      for (int c = 0; c < 8; ++c) a[c] = f32x2{-1e30f, -1e30f};   // ref NEG
    }
#pragma unroll
    for (int off = 32; off > 0; off >>= 1) {
#pragma unroll
      for (int c = 0; c < 8; ++c) {
        a[c].x = fmaxf(a[c].x, __shfl_xor(a[c].x, off, 64));
        a[c].y = fmaxf(a[c].y, __shfl_xor(a[c].y, off, 64));
      }
    }
    if (j == 0) {
#pragma unroll
      for (int c = 0; c < 8; ++c) *(f32x2*)(&R.out[g*32 + p*16 + 2*c]) = a[c];
    }
  }
  __syncthreads();
  if (t < 128) outp[t] = fmaxf(R.out[t], 0.f);
}

// ------------- rc2 item: radius(r=0.2 over pos1) + conv2 (256 thr) ----------
__device__ void rc2_item(int b, int m,
                         const float* __restrict__ x1, const float* __restrict__ pos1,
                         const unsigned int* __restrict__ sidx2, float r2,
                         const float* __restrict__ w1, const float* __restrict__ b1,
                         const float* __restrict__ w2, const float* __restrict__ b2,
                         const float* __restrict__ w3, const float* __restrict__ b3,
                         float* __restrict__ x2, SmRC2& R) {
  const int t = threadIdx.x;
  const int q = b*512 + m;
  if (t == 0) {
    unsigned int v;
    while ((v = aload(&sidx2[q])) == 0u) __builtin_amdgcn_s_sleep(16);
    R.qidx = (int)v - 1;
    R.cnt = 0;
  }
  __syncthreads();
  const float* pb = pos1 + (size_t)b * 2048 * 3;
  const int qi = R.qidx;
  const float qx = pb[qi*3], qy = pb[qi*3+1], qz = pb[qi*3+2];
  for (int i = t; i < 2048; i += 256) {
    const float d2 = d2_rn(qx, qy, qz, pb[i*3], pb[i*3+1], pb[i*3+2]);
    if (d2 <= r2) {
      const int p = atomicAdd(&R.cnt, 1);
      if (p < 1024) { R.u.rad.d2[p] = d2; R.u.rad.id[p] = i; }
    }
  }
  __syncthreads();
  const int cntc = min(R.cnt, 1024);
  const int cnt = min(cntc, 64);
  float* outp = x2 + (size_t)q * 256;
  if (cnt == 0) { outp[t] = 0.f; return; }
  if (cntc <= 64) {
    if (t < cntc) R.nid[t] = R.u.rad.id[t];
  } else {
    for (int c = t; c < cntc; c += 256) {
      const float dc = R.u.rad.d2[c]; const int ic = R.u.rad.id[c];
      int rank = 0;
      for (int jj = 0; jj < cntc; ++jj)
        rank += (R.u.rad.d2[jj] < dc) || (R.u.rad.d2[jj] == dc && R.u.rad.id[jj] < ic);
      if (rank < 64) R.nid[rank] = ic;
    }
  }
  __syncthreads();
  if (t < 64) {
    const int n = (t < cnt) ? R.nid[t] : 0;
    const float* p = pos1 + ((size_t)(b << 11) + n) * 3;
    R.rel[t*4+0] = p[0] - qx; R.rel[t*4+1] = p[1] - qy; R.rel[t*4+2] = p[2] - qz;
  }
  __syncthreads();
  float* s_x = R.u.x;    // overlays rad
  for (int i = t; i < 64*128; i += 256) {
    const int r = i >> 7, c = i & 127;
    const int n = ((r < cnt) ? R.nid[r] : 0);
    s_x[r*128 + (c ^ (r & 31))] = x1[((size_t)(b << 11) + n)*128 + c];
  }
  __syncthreads();
  const int j = t & 63;
  const int g = __builtin_amdgcn_readfirstlane(t >> 6);
  const int sw  = j & 31;
  const int row = j * 128;
  f32x2 acc[16];
  { const f32x2* bv = (const f32x2*)(b1 + g*32);
#pragma unroll
    for (int c = 0; c < 16; ++c) acc[c] = bv[c]; }
#pragma unroll 2
  for (int k = 0; k < 128; ++k) {
    const float xk = s_x[row + (k ^ sw)];
    const f32x2 xv = {xk, xk};
    const float4* wr = (const float4*)(w1 + k*128 + g*32);
#pragma unroll
    for (int c4 = 0; c4 < 8; ++c4) {
      const float4 w = wr[c4];
      acc[c4*2+0] += xv * f32x2{w.x, w.y};
      acc[c4*2+1] += xv * f32x2{w.z, w.w};
    }
  }
#pragma unroll
  for (int kk = 0; kk < 3; ++kk) {
    const float xk = R.rel[j*4 + kk];
    const f32x2 xv = {xk, xk};
    const float4* wr = (const float4*)(w1 + (128 + kk)*128 + g*32);
#pragma unroll
    for (int c4 = 0; c4 < 8; ++c4) {
      const float4 w = wr[c4];
      acc[c4*2+0] += xv * f32x2{w.x, w.y};
      acc[c4*2+1] += xv * f32x2{w.z, w.w};
    }
  }
  __syncthreads();   // all L1 reads of msg done
#pragma unroll
  for (int c = 0; c < 16; ++c) {
    const f32x2 v = acc[c];
    s_x[row + ((g*32 + 2*c + 0) ^ sw)] = fmaxf(v.x, 0.f);
    s_x[row + ((g*32 + 2*c + 1) ^ sw)] = fmaxf(v.y, 0.f);
  }
  __syncthreads();
  { const f32x2* bv = (const f32x2*)(b2 + g*32);
#pragma unroll
    for (int c = 0; c < 16; ++c) acc[c] = bv[c]; }
#pragma unroll 2
  for (int k = 0; k < 128; ++k) {
    const float hk = s_x[row + (k ^ sw)];
    const f32x2 hv = {hk, hk};
    const float4* wr = (const float4*)(w2 + k*128 + g*32);
#pragma unroll
    for (int c4 = 0; c4 < 8; ++c4) {
      const float4 w = wr[c4];
      acc[c4*2+0] += hv * f32x2{w.x, w.y};
      acc[c4*2+1] += hv * f32x2{w.z, w.w};
    }
  }
  __syncthreads();
#pragma unroll
  for (int c = 0; c < 16; ++c) {
    const f32x2 v = acc[c];
    s_x[row + ((g*32 + 2*c + 0) ^ sw)] = fmaxf(v.x, 0.f);
    s_x[row + ((g*32 + 2*c + 1) ^ sw)] = fmaxf(v.y, 0.f);
  }
  __syncthreads();
#pragma unroll 1
  for (int p = 0; p < 2; ++p) {
    f32x2 a[16];
    { const f32x2* bv = (const f32x2*)(b3 + g*64 + p*32);
#pragma unroll
      for (int c = 0; c < 16; ++c) a[c] = bv[c]; }
#pragma unroll 2
    for (int k = 0; k < 128; ++k) {
      const float hk = s_x[row + (k ^ sw)];
      const f32x2 hv = {hk, hk};
      const float4* wr = (const float4*)(w3 + k*256 + g*64 + p*32);
#pragma unroll
      for (int c4 = 0; c4 < 8; ++c4) {
        const float4 w = wr[c4];
        a[c4*2+0] += hv * f32x2{w.x, w.y};
        a[c4*2+1] += hv * f32x2{w.z, w.w};
      }
    }
    if (j >= cnt) {
#pragma unroll
      for (int c = 0; c < 16; ++c) a[c] = f32x2{-1e30f, -1e30f};
    }
#pragma unroll
    for (int off = 32; off > 0; off >>= 1) {
#pragma unroll
      for (int c = 0; c < 16; ++c) {
        a[c].x = fmaxf(a[c].x, __shfl_xor(a[c].x, off, 64));
        a[c].y = fmaxf(a[c].y, __shfl_xor(a[c].y, off, 64));
      }
    }
    if (j == 0) {
#pragma unroll
      for (int c = 0; c < 16; ++c) *(f32x2*)(&R.out[g*64 + p*32 + 2*c]) = a[c];
    }
  }
  __syncthreads();
  outp[t] = fmaxf(R.out[t], 0.f);
}

// -------------------- mega1: 8 fps1 + 16384 radius1/conv1 -------------------
__global__ __launch_bounds__(256, 1) void mega1_kernel(
    const float* __restrict__ points, float* __restrict__ pos1,
    unsigned int* __restrict__ sidx1,
    int* __restrict__ qhead, float r2,
    const float* __restrict__ w1, const float* __restrict__ b1,
    const float* __restrict__ w2, const float* __restrict__ b2,
    const float* __restrict__ w3, const float* __restrict__ b3,
    float* __restrict__ x1) {
  __shared__ Mega1Sm sm;
  __shared__ int s_item;
  const int t = threadIdx.x;
  for (;;) {
    __syncthreads();            // protect LDS reuse + s_item across items
    if (t == 0) s_item = atomicAdd(qhead, 1);
    __syncthreads();
    const int w = s_item;
    if (w >= 8 + 8*2048) return;
    if (w < 8) {
      const float* pb = points + (size_t)w * 4096 * 3;
      for (int i = t; i < 4096; i += 256)
        sm.f.xyz[i] = make_float4(pb[i*3], pb[i*3+1], pb[i*3+2], 0.f);
      __syncthreads();
      fps_core<4096, 2048, 256>(sm.f.xyz, sm.f.idx, sm.f.red,
                                pos1 + (size_t)w*2048*3, sidx1 + w*2048);
    } else {
      const int qq = w - 8;
      rc1_item(qq & 7, qq >> 3, points, sidx1, r2, w1, b1, w2, b2, w3, b3, x1, sm.r);
    }
  }
}

// -------------------- mega2: 8 fps2 + 4096 radius2/conv2 --------------------
__global__ __launch_bounds__(256, 4) void mega2_kernel(
    const float* __restrict__ x1, const float* __restrict__ pos1,
    float* __restrict__ pos2,
    unsigned int* __restrict__ sidx2, int* __restrict__ qhead, float r2,
    const float* __restrict__ w1, const float* __restrict__ b1,
    const float* __restrict__ w2, const float* __restrict__ b2,
    const float* __restrict__ w3, const float* __restrict__ b3,
    float* __restrict__ x2) {
  __shared__ Mega2Sm sm;
  __shared__ int s_item;
  const int t = threadIdx.x;
  for (;;) {
    __syncthreads();
    if (t == 0) s_item = atomicAdd(qhead, 1);
    __syncthreads();
    const int w = s_item;
    if (w >= 8 + 8*512) return;
    if (w < 8) {
      // pos1 is kernel-boundary-coherent: stage directly
      const float* pb = pos1 + (size_t)w * 2048 * 3;
      for (int i = t; i < 2048; i += 256)
        sm.f.xyz[i] = make_float4(pb[i*3], pb[i*3+1], pb[i*3+2], 0.f);
      __syncthreads();
      fps_core<2048, 512, 256>(sm.f.xyz, sm.f.idx, sm.f.red,
                               pos2 + (size_t)w*512*3, sidx2 + w*512);
    } else {
      const int qq = w - 8;
      rc2_item(qq & 7, qq >> 3, x1, pos1, sidx2, r2, w1, b1, w2, b2, w3, b3, x2, sm.r);
    }
  }
}

// --------- global MLP 259->256->512->1024, per-block(16pt) partial max ------
__global__ __launch_bounds__(256) void gmlp_kernel(
    const float* __restrict__ x2, const float* __restrict__ pos2,
    const float* __restrict__ w1, const float* __restrict__ b1,
    const float* __restrict__ w2, const float* __restrict__ b2,
    const float* __restrict__ w3, const float* __restrict__ b3,
    float* __restrict__ gpart) {
  const int blk = blockIdx.x;     // 16 points per block (group = 8 blocks)
  const int t = threadIdx.x;
  __shared__ float sA[260 * 18];  // [k][p], pad 18 for 8B alignment
  __shared__ float sB[512 * 18];
  const int p0 = blk * 16;
  for (int i = t; i < 16*256; i += 256) {
    const int p = i >> 8, k = i & 255;
    sA[k*18 + p] = x2[(size_t)(p0 + p)*256 + k];
  }
  if (t < 48) { const int p = t/3, c = t%3; sA[(256+c)*18 + p] = pos2[(size_t)(p0+p)*3 + c]; }
  __syncthreads();
  f32x2 h1[8];
  { const float bb = b1[t];
#pragma unroll
    for (int p8 = 0; p8 < 8; ++p8) h1[p8] = f32x2{bb, bb}; }
#pragma unroll 2
  for (int k = 0; k < 259; ++k) {
    const float w = w1[(size_t)k*256 + t];
    const f32x2 wv = {w, w};
    const f32x2* row = (const f32x2*)(&sA[k*18]);
#pragma unroll
    for (int p8 = 0; p8 < 8; ++p8) h1[p8] += row[p8] * wv;
  }
  __syncthreads();
#pragma unroll
  for (int p8 = 0; p8 < 8; ++p8) {
    f32x2 a = h1[p8];
    a.x = fmaxf(a.x, 0.f); a.y = fmaxf(a.y, 0.f);
    *(f32x2*)(&sA[t*18 + 2*p8]) = a;
  }
  __syncthreads();
  f32x2 h2a[8], h2b[8];
  { const float ba = b2[t], bb = b2[t + 256];
#pragma unroll
    for (int p8 = 0; p8 < 8; ++p8) { h2a[p8] = f32x2{ba, ba}; h2b[p8] = f32x2{bb, bb}; } }
#pragma unroll 2
  for (int k = 0; k < 256; ++k) {
    const float wa = w2[(size_t)k*512 + t];
    const float wb = w2[(size_t)k*512 + t + 256];
    const f32x2 wav = {wa, wa}, wbv = {wb, wb};
    const f32x2* row = (const f32x2*)(&sA[k*18]);
#pragma unroll
    for (int p8 = 0; p8 < 8; ++p8) { const f32x2 x = row[p8]; h2a[p8] += x*wav; h2b[p8] += x*wbv; }
  }
  __syncthreads();
#pragma unroll
  for (int p8 = 0; p8 < 8; ++p8) {
    f32x2 a = h2a[p8], c = h2b[p8];
    a.x = fmaxf(a.x, 0.f); a.y = fmaxf(a.y, 0.f);
    c.x = fmaxf(c.x, 0.f); c.y = fmaxf(c.y, 0.f);
    *(f32x2*)(&sB[t*18 + 2*p8]) = a;
    *(f32x2*)(&sB[(t+256)*18 + 2*p8]) = c;
  }
  __syncthreads();
  f32x2 a3[4][8];
#pragma unroll
  for (int c = 0; c < 4; ++c) {
    const float bb = b3[t + c*256];
#pragma unroll
    for (int p8 = 0; p8 < 8; ++p8) a3[c][p8] = f32x2{bb, bb};
  }
#pragma unroll 2
  for (int k = 0; k < 512; ++k) {
    const f32x2* row = (const f32x2*)(&sB[k*18]);
    f32x2 xk[8];
#pragma unroll
    for (int p8 = 0; p8 < 8; ++p8) xk[p8] = row[p8];
#pragma unroll
    for (int c = 0; c < 4; ++c) {
      const float w = w3[(size_t)k*1024 + t + c*256];
      const f32x2 wv = {w, w};
#pragma unroll
      for (int p8 = 0; p8 < 8; ++p8) a3[c][p8] += xk[p8] * wv;
    }
  }
#pragma unroll
  for (int c = 0; c < 4; ++c) {
    f32x2 m2 = a3[c][0];
#pragma unroll
    for (int p8 = 1; p8 < 8; ++p8) {
      m2.x = fmaxf(m2.x, a3[c][p8].x); m2.y = fmaxf(m2.y, a3[c][p8].y);
    }
    gpart[(size_t)blk*1024 + t + c*256] = fmaxf(m2.x, m2.y);
  }
}

// ------ head MLP: fused 8-row gpart max -> 1024->512->256->7 per row --------
__global__ __launch_bounds__(256) void head_kernel(
    const float* __restrict__ gpart,
    const float* __restrict__ l1w, const float* __restrict__ l1b,
    const float* __restrict__ l2w, const float* __restrict__ l2b,
    const float* __restrict__ l3w, const float* __restrict__ l3b,
    float* __restrict__ h3) {
  const int r = blockIdx.x, t = threadIdx.x;
  __shared__ float sIn[1024];
  __shared__ float sH[512];
  __shared__ float sH2[256];
  for (int i = t; i < 1024; i += 256) {
    float v = gpart[(size_t)(r*8)*1024 + i];
#pragma unroll
    for (int rr = 1; rr < 8; ++rr) v = fmaxf(v, gpart[(size_t)(r*8 + rr)*1024 + i]);
    sIn[i] = v;
  }
  __syncthreads();
  float a0 = l1b[t], a1 = l1b[t + 256];
#pragma unroll 4
  for (int k = 0; k < 1024; ++k) {
    const float x = sIn[k];
    a0 += x * l1w[(size_t)k*512 + t];
    a1 += x * l1w[(size_t)k*512 + t + 256];
  }
  sH[t] = fmaxf(a0, 0.f); sH[t+256] = fmaxf(a1, 0.f);
  __syncthreads();
  float a = l2b[t];
#pragma unroll 4
  for (int k = 0; k < 512; ++k) a += sH[k] * l2w[(size_t)k*256 + t];
  sH2[t] = fmaxf(a, 0.f);
  __syncthreads();
  if (t < 7) {
    float acc = l3b[t];
#pragma unroll 4
    for (int k = 0; k < 256; ++k) acc += sH2[k] * l3w[(size_t)k*7 + t];
    h3[(size_t)r*7 + t] = acc;
  }
}

// ---------------- mean over 4 group-rows + quaternion normalize -------------
__global__ void final_kernel(const float* __restrict__ h3, float* __restrict__ out) {
  const int b = threadIdx.x;
  if (b >= 8) return;
  float v[7];
#pragma unroll
  for (int c = 0; c < 7; ++c) {
    const float s = ((h3[(b*4+0)*7+c] + h3[(b*4+1)*7+c]) + h3[(b*4+2)*7+c]) + h3[(b*4+3)*7+c];
    v[c] = s * 0.25f;
  }
  const float nrm = fmaxf(sqrtf(((v[3]*v[3] + v[4]*v[4]) + v[5]*v[5]) + v[6]*v[6]), 1e-12f);
  out[b*7+0] = v[0]; out[b*7+1] = v[1]; out[b*7+2] = v[2];
  out[b*7+3] = v[3]/nrm; out[b*7+4] = v[4]/nrm;
  out[b*7+5] = v[5]/nrm; out[b*7+6] = v[6]/nrm;
}

extern "C" void kernel_launch(void* const* d_in, const int* in_sizes, int n_in,
                              void* d_out, int out_size, void* d_ws, size_t ws_size,
                              hipStream_t stream) {
  const float* points = (const float*)d_in[0];
  const float* sa1_w1 = (const float*)d_in[1];
  const float* sa1_b1 = (const float*)d_in[2];
  const float* sa1_w2 = (const float*)d_in[3];
  const float* sa1_b2 = (const float*)d_in[4];
  const float* sa1_w3 = (const float*)d_in[5];
  const float* sa1_b3 = (const float*)d_in[6];
  const float* sa2_w1 = (const float*)d_in[7];
  const float* sa2_b1 = (const float*)d_in[8];
  const float* sa2_w2 = (const float*)d_in[9];
  const float* sa2_b2 = (const float*)d_in[10];
  const float* sa2_w3 = (const float*)d_in[11];
  const float* sa2_b3 = (const float*)d_in[12];
  const float* g_w1   = (const float*)d_in[13];
  const float* g_b1   = (const float*)d_in[14];
  const float* g_w2   = (const float*)d_in[15];
  const float* g_b2   = (const float*)d_in[16];
  const float* g_w3   = (const float*)d_in[17];
  const float* g_b3   = (const float*)d_in[18];
  const float* l1_w   = (const float*)d_in[19];
  const float* l1_b   = (const float*)d_in[20];
  const float* l2_w   = (const float*)d_in[21];
  const float* l2_b   = (const float*)d_in[22];
  const float* l3_w   = (const float*)d_in[23];
  const float* l3_b   = (const float*)d_in[24];

  // Workspace: [sync region (zeroed each call)][float arrays]
  unsigned int* u = (unsigned int*)d_ws;
  unsigned int* sidx1 = u;                 // 8*2048
  unsigned int* sidx2 = u + 16384;         // 8*512
  int* qhead1 = (int*)(u + 16384 + 4096);
  int* qhead2 = qhead1 + 1;
  const size_t syncWords = 16384 + 4096 + 2;

  float* ws = (float*)d_ws + 20608;        // 64-aligned past sync region
  size_t o = 0;
  float* pos1  = ws + o; o += (size_t)8*2048*3;
  float* pos2  = ws + o; o += (size_t)8*512*3;
  float* x1    = ws + o; o += (size_t)8*2048*128;
  float* x2    = ws + o; o += (size_t)8*512*256;
  float* gpart = ws + o; o += (size_t)256*1024;
  float* h3    = ws + o; o += (size_t)32*7;

  hipMemsetAsync(d_ws, 0, syncWords * 4, stream);

  // Radius thresholds: Python computes r*r in double, JAX weak-types to f32.
  const float R2_1 = (float)(0.1 * 0.1);
  const float R2_2 = (float)(0.2 * 0.2);

  mega1_kernel<<<128, 256, 0, stream>>>(points, pos1, sidx1, qhead1, R2_1,
                                        sa1_w1, sa1_b1, sa1_w2, sa1_b2, sa1_w3, sa1_b3, x1);
  mega2_kernel<<<1024, 256, 0, stream>>>(x1, pos1, pos2, sidx2, qhead2, R2_2,
                                         sa2_w1, sa2_b1, sa2_w2, sa2_b2, sa2_w3, sa2_b3, x2);
  gmlp_kernel<<<256, 256, 0, stream>>>(x2, pos2, g_w1, g_b1, g_w2, g_b2, g_w3, g_b3, gpart);
  head_kernel<<<32, 256, 0, stream>>>(gpart, l1_w, l1_b, l2_w, l2_b, l3_w, l3_b, h3);
  final_kernel<<<1, 64, 0, stream>>>(h3, (float*)d_out);
}

// Round 13
// 2279.100 us; speedup vs baseline: 1.7847x; 1.7847x over previous
//
#include <hip/hip_runtime.h>
#include <float.h>

// CloudNet (PointNet++-ish) pipeline on MI355X — persistent-block producer/
// consumer megakernel (R9 structure) + throughput kernels. Correctness:
// FPS + radius selection bit-exact vs numpy f32 (contract(off) + __f*_rn;
// argmax/top_k ties -> lowest index). MLP math free to use pk-FMA.
//
// R13: R9 skeleton (best measured: 2387us) + R12 fps micro-opts (float4
// coords, batched pos writeout, publish-early). Union ~72KB -> 2 blocks/CU:
// each fps producer shares its CU with exactly ONE rc1 consumer.

typedef float f32x2 __attribute__((ext_vector_type(2)));

__device__ __forceinline__ float d2_rn(float ax, float ay, float az,
                                       float bx, float by, float bz) {
  float dx = __fsub_rn(ax, bx), dy = __fsub_rn(ay, by), dz = __fsub_rn(az, bz);
  return __fadd_rn(__fadd_rn(__fmul_rn(dx, dx), __fmul_rn(dy, dy)), __fmul_rn(dz, dz));
}

template<int CTRL>
__device__ __forceinline__ unsigned long long dppmax(unsigned long long a) {
  const unsigned int lo = (unsigned int)a, hi = (unsigned int)(a >> 32);
  const unsigned int slo =
      (unsigned int)__builtin_amdgcn_update_dpp(0, (int)lo, CTRL, 0xf, 0xf, true);
  const unsigned int shi =
      (unsigned int)__builtin_amdgcn_update_dpp(0, (int)hi, CTRL, 0xf, 0xf, true);
  const unsigned long long s = ((unsigned long long)shi << 32) | slo;
  return s > a ? s : a;
}

__device__ __forceinline__ unsigned int aload(const unsigned int* p) {
  return __hip_atomic_load(p, __ATOMIC_RELAXED, __HIP_MEMORY_SCOPE_AGENT);
}
__device__ __forceinline__ void astore(unsigned int* p, unsigned int v) {
  __hip_atomic_store(p, v, __ATOMIC_RELAXED, __HIP_MEMORY_SCOPE_AGENT);
}

// Barrier draining only LDS (lgkm), not vmcnt (no store-ack stall in-loop).
__device__ __forceinline__ void barrier_lgkm() {
  asm volatile("s_waitcnt lgkmcnt(0)\n\ts_barrier" ::: "memory");
}

// ---------------- FPS core (T=256, pk-f32 distance, DPP ladder) -------------
// Key = (f32_bits(mind)<<32) | (N-1-idx): u64 max == argmax with numpy's
// lowest-index tie-break. Publishes sample idx (idx+1, 0=empty) via relaxed
// device-scope atomic in-loop (consumers + fps2 staging read coords from the
// immutable source array); pos coords written batched at the end.
template<int N, int NS, int T>
__device__ void fps_core(float4* sxyz, int* s_idx,
                         unsigned long long* s_red,
                         float* __restrict__ outp,
                         unsigned int* __restrict__ pub) {
#pragma clang fp contract(off)
  constexpr int P = N / T;
  constexpr int P2 = P / 2;
  constexpr int W = T / 64;
  const int t = threadIdx.x;
  __builtin_amdgcn_s_setprio(2);
  f32x2 px[P2], py[P2], pz[P2], mind[P2];
  unsigned int kc0[P2], kc1[P2];
#pragma unroll
  for (int j = 0; j < P2; ++j) {
    const int i0 = (2*j)*T + t, i1 = i0 + T;
    const float4 c0 = sxyz[i0], c1 = sxyz[i1];
    px[j] = f32x2{c0.x, c1.x};
    py[j] = f32x2{c0.y, c1.y};
    pz[j] = f32x2{c0.z, c1.z};
    mind[j] = f32x2{FLT_MAX, FLT_MAX};    // ref inits to finfo(f32).max
    kc0[j] = (unsigned int)(N - 1 - i0);
    kc1[j] = (unsigned int)(N - 1 - i1);
  }
  float lx = sxyz[0].x, ly = sxyz[0].y, lz = sxyz[0].z;  // start at point 0
  if (t == 0) { s_idx[0] = 0; astore(&pub[0], 1u); }
  for (int it = 1; it < NS; ++it) {
    const f32x2 lx2 = {lx, lx}, ly2 = {ly, ly}, lz2 = {lz, lz};
    float bv0 = -1.0f, bv1 = -1.0f;
    unsigned int bk0 = 0, bk1 = 0;
#pragma unroll
    for (int j = 0; j < P2; ++j) {
      // contract(off): separate pk_mul/pk_add — bit-exact vs numpy ufuncs
      const f32x2 dx = px[j] - lx2;
      const f32x2 dy = py[j] - ly2;
      const f32x2 dz = pz[j] - lz2;
      const f32x2 s = ((dx*dx) + (dy*dy)) + (dz*dz);
      const float m0 = fminf(mind[j].x, s.x);
      const float m1 = fminf(mind[j].y, s.y);
      mind[j] = f32x2{m0, m1};
      const bool g0 = m0 > bv0;   // strict > => lowest j (= lowest idx) wins
      bv0 = g0 ? m0 : bv0; bk0 = g0 ? kc0[j] : bk0;
      const bool g1 = m1 > bv1;
      bv1 = g1 ? m1 : bv1; bk1 = g1 ? kc1[j] : bk1;
    }
    const unsigned long long k0 = ((unsigned long long)__float_as_uint(bv0) << 32) | bk0;
    const unsigned long long k1 = ((unsigned long long)__float_as_uint(bv1) << 32) | bk1;
    unsigned long long key = k0 > k1 ? k0 : k1;   // ties: larger kc = lower idx
    key = dppmax<0x111>(key);  // row_shr:1
    key = dppmax<0x112>(key);  // row_shr:2
    key = dppmax<0x114>(key);  // row_shr:4
    key = dppmax<0x118>(key);  // row_shr:8
    key = dppmax<0x142>(key);  // row_bcast:15
    key = dppmax<0x143>(key);  // row_bcast:31  -> lane 63 holds wave max
    const int par = it & 1;
    if ((t & 63) == 63) s_red[par*W + (t >> 6)] = key;
    barrier_lgkm();
    unsigned long long best = s_red[par*W];
#pragma unroll
    for (int w = 1; w < W; ++w) {
      const unsigned long long o = s_red[par*W + w];
      best = o > best ? o : best;
    }
    const int idx = (N - 1) - (int)(unsigned int)(best & 0xFFFFFFFFull);
    // publish early: next-iter VALU covers store latency (no vm drain at barrier)
    if (t == 0) { astore(&pub[it], (unsigned int)(idx + 1)); s_idx[it] = idx; }
    const float4 c = sxyz[idx];           // single b128 broadcast
    lx = c.x; ly = c.y; lz = c.z;
  }
  __builtin_amdgcn_s_setprio(0);
  __syncthreads();
  for (int s = t; s < NS; s += T) {       // batched coord writeout
    const float4 c = sxyz[s_idx[s]];
    outp[(size_t)s*3 + 0] = c.x; outp[(size_t)s*3 + 1] = c.y; outp[(size_t)s*3 + 2] = c.z;
  }
}

// ----------------------------- LDS layouts ----------------------------------
struct FpsSm { float4 xyz[4096]; int idx[2048]; unsigned long long red[8]; };
struct SmRC1 {
  union { struct { float d2[1024]; int id[1024]; } rad; float x[64 * 64]; } u;
  float rel[64 * 4];
  float out[128];
  int nid[64];
  int qidx;
  int cnt;
};
struct SmRC2 {
  union { struct { float d2[1024]; int id[1024]; } rad; float x[64 * 128]; } u;
  float rel[64 * 4];
  float out[256];
  int nid[64];
  int qidx;
  int cnt;
};
// ~72KB -> exactly 2 blocks/CU: producer + 1 consumer per CU.
union Mega1Sm { FpsSm f; SmRC1 r; };

// ------------- rc1 item: radius(r=0.1 over points) + conv1 (256 thr) --------
__device__ void rc1_item(int b, int m,
                         const float* __restrict__ points,
                         const unsigned int* __restrict__ sidx1, float r2,
                         const float* __restrict__ w1, const float* __restrict__ b1,
                         const float* __restrict__ w2, const float* __restrict__ b2,
                         const float* __restrict__ w3, const float* __restrict__ b3,
                         float* __restrict__ x1, SmRC1& R) {
  const int t = threadIdx.x;
  const int q = b*2048 + m;
  if (t == 0) {
    unsigned int v;
    while ((v = aload(&sidx1[q])) == 0u) __builtin_amdgcn_s_sleep(16);
    R.qidx = (int)v - 1;
    R.cnt = 0;
  }
  __syncthreads();
  const float* pb = points + (size_t)b * 4096 * 3;
  const int qi = R.qidx;
  const float qx = pb[qi*3], qy = pb[qi*3+1], qz = pb[qi*3+2];
  for (int i = t; i < 4096; i += 256) {
    const float d2 = d2_rn(qx, qy, qz, pb[i*3], pb[i*3+1], pb[i*3+2]);
    if (d2 <= r2) {
      const int p = atomicAdd(&R.cnt, 1);
      if (p < 1024) { R.u.rad.d2[p] = d2; R.u.rad.id[p] = i; }
    }
  }
  __syncthreads();
  const int cntc = min(R.cnt, 1024);
  const int cnt = min(cntc, 64);
  float* outp = x1 + (size_t)q * 128;
  if (cnt == 0) { if (t < 128) outp[t] = 0.f; return; }
  if (cntc <= 64) {
    if (t < cntc) R.nid[t] = R.u.rad.id[t];     // set equality suffices (max-agg)
  } else {
    // top_k(-d2): smallest d2, ties -> lower index. (d2,idx) lex rank < 64.
    for (int c = t; c < cntc; c += 256) {
      const float dc = R.u.rad.d2[c]; const int ic = R.u.rad.id[c];
      int rank = 0;
      for (int jj = 0; jj < cntc; ++jj)
        rank += (R.u.rad.d2[jj] < dc) || (R.u.rad.d2[jj] == dc && R.u.rad.id[jj] < ic);
      if (rank < 64) R.nid[rank] = ic;
    }
  }
  __syncthreads();
  if (t < 64) {
    const int n = (t < cnt) ? R.nid[t] : 0;     // finite filler row
    const float* p = points + ((size_t)(b << 12) + n) * 3;
    R.rel[t*4+0] = p[0] - qx; R.rel[t*4+1] = p[1] - qy; R.rel[t*4+2] = p[2] - qz;
  }
  __syncthreads();
  // conv1: rel(3)->64->64->128, 4 waves x 16-ch slices, h in LDS (5-bit XOR)
  const int j = t & 63;
  const int g = __builtin_amdgcn_readfirstlane(t >> 6);
  float* s_x = R.u.x;    // overlays rad (done)
  const int sw  = j & 31;
  const int row = j * 64;
  const float rx = R.rel[j*4+0], ry = R.rel[j*4+1], rz = R.rel[j*4+2];
  f32x2 acc[8];
  { const f32x2* bv = (const f32x2*)(b1 + g*16);
#pragma unroll
    for (int c = 0; c < 8; ++c) acc[c] = bv[c]; }
#pragma unroll
  for (int kk = 0; kk < 3; ++kk) {
    const float xk = (kk == 0) ? rx : ((kk == 1) ? ry : rz);
    const f32x2 xv = {xk, xk};
    const float4* wr = (const float4*)(w1 + kk*64 + g*16);
#pragma unroll
    for (int c4 = 0; c4 < 4; ++c4) {
      const float4 w = wr[c4];
      acc[c4*2+0] += xv * f32x2{w.x, w.y};
      acc[c4*2+1] += xv * f32x2{w.z, w.w};
    }
  }
#pragma unroll
  for (int c = 0; c < 8; ++c) {
    const f32x2 v = acc[c];
    s_x[row + ((g*16 + 2*c + 0) ^ sw)] = fmaxf(v.x, 0.f);
    s_x[row + ((g*16 + 2*c + 1) ^ sw)] = fmaxf(v.y, 0.f);
  }
  __syncthreads();
  { const f32x2* bv = (const f32x2*)(b2 + g*16);
#pragma unroll
    for (int c = 0; c < 8; ++c) acc[c] = bv[c]; }
#pragma unroll 2
  for (int k = 0; k < 64; ++k) {
    const float hk = s_x[row + (k ^ sw)];
    const f32x2 hv = {hk, hk};
    const float4* wr = (const float4*)(w2 + k*64 + g*16);
#pragma unroll
    for (int c4 = 0; c4 < 4; ++c4) {
      const float4 w = wr[c4];
      acc[c4*2+0] += hv * f32x2{w.x, w.y};
      acc[c4*2+1] += hv * f32x2{w.z, w.w};
    }
  }
  __syncthreads();   // all L2 reads of h1 done
#pragma unroll
  for (int c = 0; c < 8; ++c) {
    const f32x2 v = acc[c];
    s_x[row + ((g*16 + 2*c + 0) ^ sw)] = fmaxf(v.x, 0.f);
    s_x[row + ((g*16 + 2*c + 1) ^ sw)] = fmaxf(v.y, 0.f);
  }
  __syncthreads();
#pragma unroll 1
  for (int p = 0; p < 2; ++p) {
    f32x2 a[8];
    { const f32x2* bv = (const f32x2*)(b3 + g*32 + p*16);
#pragma unroll
      for (int c = 0; c < 8; ++c) a[c] = bv[c]; }
#pragma unroll 2
    for (int k = 0; k < 64; ++k) {
      const float hk = s_x[row + (k ^ sw)];
      const f32x2 hv = {hk, hk};
      const float4* wr = (const float4*)(w3 + k*128 + g*32 + p*16);
#pragma unroll
      for (int c4 = 0; c4 < 4; ++c4) {
        const float4 w = wr[c4];
        a[c4*2+0] += hv * f32x2{w.x, w.y};
        a[c4*2+1] += hv * f32x2{w.z, w.w};
      }
    }
    if (j >= cnt) {
#pragma unroll
      for (int c = 0; c < 8; ++c) a[c] = f32x2{-1e30f, -1e30f};   // ref NEG
    }
#pragma unroll
    for (int off = 32; off > 0; off >>= 1) {
#pragma unroll
      for (int c = 0; c < 8; ++c) {
        a[c].x = fmaxf(a[c].x, __shfl_xor(a[c].x, off, 64));
        a[c].y = fmaxf(a[c].y, __shfl_xor(a[c].y, off, 64));
      }
    }
    if (j == 0) {
#pragma unroll
      for (int c = 0; c < 8; ++c) *(f32x2*)(&R.out[g*32 + p*16 + 2*c]) = a[c];
    }
  }
  __syncthreads();
  if (t < 128) outp[t] = fmaxf(R.out[t], 0.f);
}

// ---- mega1: 8 fps1 + 8 fps2 (spin-staged) + 16384 radius1/conv1 items ------
__global__ __launch_bounds__(256, 2) void mega1_kernel(
    const float* __restrict__ points, float* __restrict__ pos1,
    float* __restrict__ pos2,
    unsigned int* __restrict__ sidx1, unsigned int* __restrict__ sidx2,
    int* __restrict__ qhead, float r2,
    const float* __restrict__ w1, const float* __restrict__ b1,
    const float* __restrict__ w2, const float* __restrict__ b2,
    const float* __restrict__ w3, const float* __restrict__ b3,
    float* __restrict__ x1) {
  __shared__ Mega1Sm sm;
  __shared__ int s_item;
  const int t = threadIdx.x;
  for (;;) {
    __syncthreads();            // protect LDS reuse + s_item across items
    if (t == 0) s_item = atomicAdd(qhead, 1);
    __syncthreads();
    const int w = s_item;
    if (w >= 16 + 8*2048) return;
    if (w < 8) {
      // fps1 for cloud w: stage contiguous
      const float* pb = points + (size_t)w * 4096 * 3;
      for (int i = t; i < 4096; i += 256)
        sm.f.xyz[i] = make_float4(pb[i*3], pb[i*3+1], pb[i*3+2], 0.f);
      __syncthreads();
      fps_core<4096, 2048, 256>(sm.f.xyz, sm.f.idx, sm.f.red,
                                pos1 + (size_t)w*2048*3, sidx1 + w*2048);
    } else if (w < 16) {
      // fps2 for cloud b: stage via per-element spin on sidx1 (coherent:
      // atomics + immutable points only)
      const int b = w - 8;
      const float* pb = points + (size_t)b * 4096 * 3;
      for (int i = t; i < 2048; i += 256) {
        unsigned int v;
        while ((v = aload(&sidx1[b*2048 + i])) == 0u) __builtin_amdgcn_s_sleep(16);
        const int idx = (int)v - 1;
        sm.f.xyz[i] = make_float4(pb[idx*3], pb[idx*3+1], pb[idx*3+2], 0.f);
      }
      __syncthreads();
      fps_core<2048, 512, 256>(sm.f.xyz, sm.f.idx, sm.f.red,
                               pos2 + (size_t)b*512*3, sidx2 + b*512);
    } else {
      const int qq = w - 16;
      rc1_item(qq & 7, qq >> 3, points, sidx1, r2, w1, b1, w2, b2, w3, b3, x1, sm.r);
    }
  }
}

// ------------- rc2: radius(r=0.2 over pos1) + conv2, direct-mapped ----------
__global__ __launch_bounds__(256, 4) void rc2_kernel(
    const float* __restrict__ x1, const float* __restrict__ pos1,
    const unsigned int* __restrict__ sidx2, float r2,
    const float* __restrict__ w1, const float* __restrict__ b1,
    const float* __restrict__ w2, const float* __restrict__ b2,
    const float* __restrict__ w3, const float* __restrict__ b3,
    float* __restrict__ x2) {
  __shared__ SmRC2 R;
  const int q = blockIdx.x;   // b*512 + m
  const int b = q >> 9;
  const int t = threadIdx.x;
  if (t == 0) {
    unsigned int v;
    while ((v = aload(&sidx2[q])) == 0u) __builtin_amdgcn_s_sleep(16);
    R.qidx = (int)v - 1;
    R.cnt = 0;
  }
  __syncthreads();
  const float* pb = pos1 + (size_t)b * 2048 * 3;
  const int qi = R.qidx;
  const float qx = pb[qi*3], qy = pb[qi*3+1], qz = pb[qi*3+2];
  for (int i = t; i < 2048; i += 256) {
    const float d2 = d2_rn(qx, qy, qz, pb[i*3], pb[i*3+1], pb[i*3+2]);
    if (d2 <= r2) {
      const int p = atomicAdd(&R.cnt, 1);
      if (p < 1024) { R.u.rad.d2[p] = d2; R.u.rad.id[p] = i; }
    }
  }
  __syncthreads();
  const int cntc = min(R.cnt, 1024);
  const int cnt = min(cntc, 64);
  float* outp = x2 + (size_t)q * 256;
  if (cnt == 0) { outp[t] = 0.f; return; }
  if (cntc <= 64) {
    if (t < cntc) R.nid[t] = R.u.rad.id[t];
  } else {
    for (int c = t; c < cntc; c += 256) {
      const float dc = R.u.rad.d2[c]; const int ic = R.u.rad.id[c];
      int rank = 0;
      for (int jj = 0; jj < cntc; ++jj)
        rank += (R.u.rad.d2[jj] < dc) || (R.u.rad.d2[jj] == dc && R.u.rad.id[jj] < ic);
      if (rank < 64) R.nid[rank] = ic;
    }
  }
  __syncthreads();
  if (t < 64) {
    const int n = (t < cnt) ? R.nid[t] : 0;
    const float* p = pos1 + ((size_t)(b << 11) + n) * 3;
    R.rel[t*4+0] = p[0] - qx; R.rel[t*4+1] = p[1] - qy; R.rel[t*4+2] = p[2] - qz;
  }
  __syncthreads();
  float* s_x = R.u.x;    // overlays rad
  for (int i = t; i < 64*128; i += 256) {
    const int r = i >> 7, c = i & 127;
    const int n = ((r < cnt) ? R.nid[r] : 0);
    s_x[r*128 + (c ^ (r & 31))] = x1[((size_t)(b << 11) + n)*128 + c];
  }
  __syncthreads();
  const int j = t & 63;
  const int g = __builtin_amdgcn_readfirstlane(t >> 6);
  const int sw  = j & 31;
  const int row = j * 128;
  f32x2 acc[16];
  { const f32x2* bv = (const f32x2*)(b1 + g*32);
#pragma unroll
    for (int c = 0; c < 16; ++c) acc[c] = bv[c]; }
#pragma unroll 2
  for (int k = 0; k < 128; ++k) {
    const float xk = s_x[row + (k ^ sw)];
    const f32x2 xv = {xk, xk};
    const float4* wr = (const float4*)(w1 + k*128 + g*32);
#pragma unroll
    for (int c4 = 0; c4 < 8; ++c4) {
      const float4 w = wr[c4];
      acc[c4*2+0] += xv * f32x2{w.x, w.y};
      acc[c4*2+1] += xv * f32x2{w.z, w.w};
    }
  }
#pragma unroll
  for (int kk = 0; kk < 3; ++kk) {
    const float xk = R.rel[j*4 + kk];
    const f32x2 xv = {xk, xk};
    const float4* wr = (const float4*)(w1 + (128 + kk)*128 + g*32);
#pragma unroll
    for (int c4 = 0; c4 < 8; ++c4) {
      const float4 w = wr[c4];
      acc[c4*2+0] += xv * f32x2{w.x, w.y};
      acc[c4*2+1] += xv * f32x2{w.z, w.w};
    }
  }
  __syncthreads();   // all L1 reads of msg done
#pragma unroll
  for (int c = 0; c < 16; ++c) {
    const f32x2 v = acc[c];
    s_x[row + ((g*32 + 2*c + 0) ^ sw)] = fmaxf(v.x, 0.f);
    s_x[row + ((g*32 + 2*c + 1) ^ sw)] = fmaxf(v.y, 0.f);
  }
  __syncthreads();
  { const f32x2* bv = (const f32x2*)(b2 + g*32);
#pragma unroll
    for (int c = 0; c < 16; ++c) acc[c] = bv[c]; }
#pragma unroll 2
  for (int k = 0; k < 128; ++k) {
    const float hk = s_x[row + (k ^ sw)];
    const f32x2 hv = {hk, hk};
    const float4* wr = (const float4*)(w2 + k*128 + g*32);
#pragma unroll
    for (int c4 = 0; c4 < 8; ++c4) {
      const float4 w = wr[c4];
      acc[c4*2+0] += hv * f32x2{w.x, w.y};
      acc[c4*2+1] += hv * f32x2{w.z, w.w};
    }
  }
  __syncthreads();
#pragma unroll
  for (int c = 0; c < 16; ++c) {
    const f32x2 v = acc[c];
    s_x[row + ((g*32 + 2*c + 0) ^ sw)] = fmaxf(v.x, 0.f);
    s_x[row + ((g*32 + 2*c + 1) ^ sw)] = fmaxf(v.y, 0.f);
  }
  __syncthreads();
#pragma unroll 1
  for (int p = 0; p < 2; ++p) {
    f32x2 a[16];
    { const f32x2* bv = (const f32x2*)(b3 + g*64 + p*32);
#pragma unroll
      for (int c = 0; c < 16; ++c) a[c] = bv[c]; }
#pragma unroll 2
    for (int k = 0; k < 128; ++k) {
      const float hk = s_x[row + (k ^ sw)];
      const f32x2 hv = {hk, hk};
      const float4* wr = (const float4*)(w3 + k*256 + g*64 + p*32);
#pragma unroll
      for (int c4 = 0; c4 < 8; ++c4) {
        const float4 w = wr[c4];
        a[c4*2+0] += hv * f32x2{w.x, w.y};
        a[c4*2+1] += hv * f32x2{w.z, w.w};
      }
    }
    if (j >= cnt) {
#pragma unroll
      for (int c = 0; c < 16; ++c) a[c] = f32x2{-1e30f, -1e30f};
    }
#pragma unroll
    for (int off = 32; off > 0; off >>= 1) {
#pragma unroll
      for (int c = 0; c < 16; ++c) {
        a[c].x = fmaxf(a[c].x, __shfl_xor(a[c].x, off, 64));
        a[c].y = fmaxf(a[c].y, __shfl_xor(a[c].y, off, 64));
      }
    }
    if (j == 0) {
#pragma unroll
      for (int c = 0; c < 16; ++c) *(f32x2*)(&R.out[g*64 + p*32 + 2*c]) = a[c];
    }
  }
  __syncthreads();
  outp[t] = fmaxf(R.out[t], 0.f);
}

// --------- global MLP 259->256->512->1024, per-block(16pt) partial max ------
__global__ __launch_bounds__(256) void gmlp_kernel(
    const float* __restrict__ x2, const float* __restrict__ pos2,
    const float* __restrict__ w1, const float* __restrict__ b1,
    const float* __restrict__ w2, const float* __restrict__ b2,
    const float* __restrict__ w3, const float* __restrict__ b3,
    float* __restrict__ gpart) {
  const int blk = blockIdx.x;     // 16 points per block (group = 8 blocks)
  const int t = threadIdx.x;
  __shared__ float sA[260 * 18];  // [k][p], pad 18 for 8B alignment
  __shared__ float sB[512 * 18];
  const int p0 = blk * 16;
  for (int i = t; i < 16*256; i += 256) {
    const int p = i >> 8, k = i & 255;
    sA[k*18 + p] = x2[(size_t)(p0 + p)*256 + k];
  }
  if (t < 48) { const int p = t/3, c = t%3; sA[(256+c)*18 + p] = pos2[(size_t)(p0+p)*3 + c]; }
  __syncthreads();
  f32x2 h1[8];
  { const float bb = b1[t];
#pragma unroll
    for (int p8 = 0; p8 < 8; ++p8) h1[p8] = f32x2{bb, bb}; }
#pragma unroll 2
  for (int k = 0; k < 259; ++k) {
    const float w = w1[(size_t)k*256 + t];
    const f32x2 wv = {w, w};
    const f32x2* row = (const f32x2*)(&sA[k*18]);
#pragma unroll
    for (int p8 = 0; p8 < 8; ++p8) h1[p8] += row[p8] * wv;
  }
  __syncthreads();
#pragma unroll
  for (int p8 = 0; p8 < 8; ++p8) {
    f32x2 a = h1[p8];
    a.x = fmaxf(a.x, 0.f); a.y = fmaxf(a.y, 0.f);
    *(f32x2*)(&sA[t*18 + 2*p8]) = a;
  }
  __syncthreads();
  f32x2 h2a[8], h2b[8];
  { const float ba = b2[t], bb = b2[t + 256];
#pragma unroll
    for (int p8 = 0; p8 < 8; ++p8) { h2a[p8] = f32x2{ba, ba}; h2b[p8] = f32x2{bb, bb}; } }
#pragma unroll 2
  for (int k = 0; k < 256; ++k) {
    const float wa = w2[(size_t)k*512 + t];
    const float wb = w2[(size_t)k*512 + t + 256];
    const f32x2 wav = {wa, wa}, wbv = {wb, wb};
    const f32x2* row = (const f32x2*)(&sA[k*18]);
#pragma unroll
    for (int p8 = 0; p8 < 8; ++p8) { const f32x2 x = row[p8]; h2a[p8] += x*wav; h2b[p8] += x*wbv; }
  }
  __syncthreads();
#pragma unroll
  for (int p8 = 0; p8 < 8; ++p8) {
    f32x2 a = h2a[p8], c = h2b[p8];
    a.x = fmaxf(a.x, 0.f); a.y = fmaxf(a.y, 0.f);
    c.x = fmaxf(c.x, 0.f); c.y = fmaxf(c.y, 0.f);
    *(f32x2*)(&sB[t*18 + 2*p8]) = a;
    *(f32x2*)(&sB[(t+256)*18 + 2*p8]) = c;
  }
  __syncthreads();
  f32x2 a3[4][8];
#pragma unroll
  for (int c = 0; c < 4; ++c) {
    const float bb = b3[t + c*256];
#pragma unroll
    for (int p8 = 0; p8 < 8; ++p8) a3[c][p8] = f32x2{bb, bb};
  }
#pragma unroll 2
  for (int k = 0; k < 512; ++k) {
    const f32x2* row = (const f32x2*)(&sB[k*18]);
    f32x2 xk[8];
#pragma unroll
    for (int p8 = 0; p8 < 8; ++p8) xk[p8] = row[p8];
#pragma unroll
    for (int c = 0; c < 4; ++c) {
      const float w = w3[(size_t)k*1024 + t + c*256];
      const f32x2 wv = {w, w};
#pragma unroll
      for (int p8 = 0; p8 < 8; ++p8) a3[c][p8] += xk[p8] * wv;
    }
  }
#pragma unroll
  for (int c = 0; c < 4; ++c) {
    f32x2 m2 = a3[c][0];
#pragma unroll
    for (int p8 = 1; p8 < 8; ++p8) {
      m2.x = fmaxf(m2.x, a3[c][p8].x); m2.y = fmaxf(m2.y, a3[c][p8].y);
    }
    gpart[(size_t)blk*1024 + t + c*256] = fmaxf(m2.x, m2.y);
  }
}

// ------ head MLP: fused 8-row gpart max -> 1024->512->256->7 per row --------
__global__ __launch_bounds__(256) void head_kernel(
    const float* __restrict__ gpart,
    const float* __restrict__ l1w, const float* __restrict__ l1b,
    const float* __restrict__ l2w, const float* __restrict__ l2b,
    const float* __restrict__ l3w, const float* __restrict__ l3b,
    float* __restrict__ h3) {
  const int r = blockIdx.x, t = threadIdx.x;
  __shared__ float sIn[1024];
  __shared__ float sH[512];
  __shared__ float sH2[256];
  for (int i = t; i < 1024; i += 256) {
    float v = gpart[(size_t)(r*8)*1024 + i];
#pragma unroll
    for (int rr = 1; rr < 8; ++rr) v = fmaxf(v, gpart[(size_t)(r*8 + rr)*1024 + i]);
    sIn[i] = v;
  }
  __syncthreads();
  float a0 = l1b[t], a1 = l1b[t + 256];
#pragma unroll 4
  for (int k = 0; k < 1024; ++k) {
    const float x = sIn[k];
    a0 += x * l1w[(size_t)k*512 + t];
    a1 += x * l1w[(size_t)k*512 + t + 256];
  }
  sH[t] = fmaxf(a0, 0.f); sH[t+256] = fmaxf(a1, 0.f);
  __syncthreads();
  float a = l2b[t];
#pragma unroll 4
  for (int k = 0; k < 512; ++k) a += sH[k] * l2w[(size_t)k*256 + t];
  sH2[t] = fmaxf(a, 0.f);
  __syncthreads();
  if (t < 7) {
    float acc = l3b[t];
#pragma unroll 4
    for (int k = 0; k < 256; ++k) acc += sH2[k] * l3w[(size_t)k*7 + t];
    h3[(size_t)r*7 + t] = acc;
  }
}

// ---------------- mean over 4 group-rows + quaternion normalize -------------
__global__ void final_kernel(const float* __restrict__ h3, float* __restrict__ out) {
  const int b = threadIdx.x;
  if (b >= 8) return;
  float v[7];
#pragma unroll
  for (int c = 0; c < 7; ++c) {
    const float s = ((h3[(b*4+0)*7+c] + h3[(b*4+1)*7+c]) + h3[(b*4+2)*7+c]) + h3[(b*4+3)*7+c];
    v[c] = s * 0.25f;
  }
  const float nrm = fmaxf(sqrtf(((v[3]*v[3] + v[4]*v[4]) + v[5]*v[5]) + v[6]*v[6]), 1e-12f);
  out[b*7+0] = v[0]; out[b*7+1] = v[1]; out[b*7+2] = v[2];
  out[b*7+3] = v[3]/nrm; out[b*7+4] = v[4]/nrm;
  out[b*7+5] = v[5]/nrm; out[b*7+6] = v[6]/nrm;
}

extern "C" void kernel_launch(void* const* d_in, const int* in_sizes, int n_in,
                              void* d_out, int out_size, void* d_ws, size_t ws_size,
                              hipStream_t stream) {
  const float* points = (const float*)d_in[0];
  const float* sa1_w1 = (const float*)d_in[1];
  const float* sa1_b1 = (const float*)d_in[2];
  const float* sa1_w2 = (const float*)d_in[3];
  const float* sa1_b2 = (const float*)d_in[4];
  const float* sa1_w3 = (const float*)d_in[5];
  const float* sa1_b3 = (const float*)d_in[6];
  const float* sa2_w1 = (const float*)d_in[7];
  const float* sa2_b1 = (const float*)d_in[8];
  const float* sa2_w2 = (const float*)d_in[9];
  const float* sa2_b2 = (const float*)d_in[10];
  const float* sa2_w3 = (const float*)d_in[11];
  const float* sa2_b3 = (const float*)d_in[12];
  const float* g_w1   = (const float*)d_in[13];
  const float* g_b1   = (const float*)d_in[14];
  const float* g_w2   = (const float*)d_in[15];
  const float* g_b2   = (const float*)d_in[16];
  const float* g_w3   = (const float*)d_in[17];
  const float* g_b3   = (const float*)d_in[18];
  const float* l1_w   = (const float*)d_in[19];
  const float* l1_b   = (const float*)d_in[20];
  const float* l2_w   = (const float*)d_in[21];
  const float* l2_b   = (const float*)d_in[22];
  const float* l3_w   = (const float*)d_in[23];
  const float* l3_b   = (const float*)d_in[24];

  // Workspace: [sync region (zeroed each call)][float arrays]
  unsigned int* u = (unsigned int*)d_ws;
  unsigned int* sidx1 = u;                 // 8*2048
  unsigned int* sidx2 = u + 16384;         // 8*512
  int* qhead1 = (int*)(u + 16384 + 4096);
  const size_t syncWords = 16384 + 4096 + 1;

  float* ws = (float*)d_ws + 20608;        // 64-aligned past sync region
  size_t o = 0;
  float* pos1  = ws + o; o += (size_t)8*2048*3;
  float* pos2  = ws + o; o += (size_t)8*512*3;
  float* x1    = ws + o; o += (size_t)8*2048*128;
  float* x2    = ws + o; o += (size_t)8*512*256;
  float* gpart = ws + o; o += (size_t)256*1024;
  float* h3    = ws + o; o += (size_t)32*7;

  hipMemsetAsync(d_ws, 0, syncWords * 4, stream);

  // Radius thresholds: Python computes r*r in double, JAX weak-types to f32.
  const float R2_1 = (float)(0.1 * 0.1);
  const float R2_2 = (float)(0.2 * 0.2);

  mega1_kernel<<<512, 256, 0, stream>>>(points, pos1, pos2, sidx1, sidx2, qhead1, R2_1,
                                        sa1_w1, sa1_b1, sa1_w2, sa1_b2, sa1_w3, sa1_b3, x1);
  rc2_kernel<<<8*512, 256, 0, stream>>>(x1, pos1, sidx2, R2_2,
                                        sa2_w1, sa2_b1, sa2_w2, sa2_b2, sa2_w3, sa2_b3, x2);
  gmlp_kernel<<<256, 256, 0, stream>>>(x2, pos2, g_w1, g_b1, g_w2, g_b2, g_w3, g_b3, gpart);
  head_kernel<<<32, 256, 0, stream>>>(gpart, l1_w, l1_b, l2_w, l2_b, l3_w, l3_b, h3);
  final_kernel<<<1, 64, 0, stream>>>(h3, (float*)d_out);
}